// Round 10
// baseline (200.334 us; speedup 1.0000x reference)
//
#include <hip/hip_runtime.h>

#define H_DIM 4096
#define DH 1024
#define NROWS 1024

typedef __attribute__((ext_vector_type(8))) short short8;
typedef __attribute__((ext_vector_type(4))) short short4v;
typedef __attribute__((ext_vector_type(4))) float f32x4;

#define AS_GLOBAL __attribute__((address_space(1)))
#define AS_LDS __attribute__((address_space(3)))

__device__ __forceinline__ short f2bf(float f) {
  union { float f; unsigned u; } v; v.f = f;
  unsigned r = v.u + 0x7fffu + ((v.u >> 16) & 1u);
  return (short)(r >> 16);
}
__device__ __forceinline__ float bf2f(short s) {
  union { unsigned u; float f; } v;
  v.u = ((unsigned)(unsigned short)s) << 16;
  return v.f;
}

__device__ __forceinline__ void gload16(const void* g, void* l) {
  __builtin_amdgcn_global_load_lds((const AS_GLOBAL void*)g, (AS_LDS void*)l, 16, 0, 0);
}

// ---------------- bf16 converts ----------------
__global__ void convert_nodes(const float* __restrict__ n1, const float* __restrict__ n2,
                              short* __restrict__ o1, short* __restrict__ o2) {
  const float* src = blockIdx.y ? n2 : n1;
  short* dst = blockIdx.y ? o2 : o1;
  const size_t i = ((size_t)blockIdx.x * 256 + threadIdx.x) * 8;
  f32x4 a = *(const f32x4*)&src[i];
  f32x4 b = *(const f32x4*)&src[i + 4];
  short8 s;
  s[0] = f2bf(a.x); s[1] = f2bf(a.y); s[2] = f2bf(a.z); s[3] = f2bf(a.w);
  s[4] = f2bf(b.x); s[5] = f2bf(b.y); s[6] = f2bf(b.z); s[7] = f2bf(b.w);
  *(short8*)&dst[i] = s;
}

// W [4][4096][1024] f32 -> Wt [12][1024][4096] bf16 (transpose per head); z picks q/k/v+head
__global__ void convert_w_all(const float* __restrict__ Wq, const float* __restrict__ Wk,
                              const float* __restrict__ Wv, short* __restrict__ Wt) {
  __shared__ short tile[64][72];
  const int z = blockIdx.z, dt = blockIdx.y, ft = blockIdx.x;
  const float* W = (z < 4) ? Wq : (z < 8) ? Wk : Wv;
  const int h = z & 3;
  const float* Wh = W + (size_t)h * H_DIM * DH;
  short* Wth = Wt + (size_t)z * DH * H_DIM;
  const int t = threadIdx.x;
  {
    const int d = t >> 2, f0 = (t & 3) * 16;
    const float* src = Wh + (size_t)(dt * 64 + d) * DH + ft * 64 + f0;
    f32x4 v0 = *(const f32x4*)(src + 0);
    f32x4 v1 = *(const f32x4*)(src + 4);
    f32x4 v2 = *(const f32x4*)(src + 8);
    f32x4 v3 = *(const f32x4*)(src + 12);
    short8 s0, s1;
    s0[0] = f2bf(v0.x); s0[1] = f2bf(v0.y); s0[2] = f2bf(v0.z); s0[3] = f2bf(v0.w);
    s0[4] = f2bf(v1.x); s0[5] = f2bf(v1.y); s0[6] = f2bf(v1.z); s0[7] = f2bf(v1.w);
    s1[0] = f2bf(v2.x); s1[1] = f2bf(v2.y); s1[2] = f2bf(v2.z); s1[3] = f2bf(v2.w);
    s1[4] = f2bf(v3.x); s1[5] = f2bf(v3.y); s1[6] = f2bf(v3.z); s1[7] = f2bf(v3.w);
    *(short8*)&tile[d][f0] = s0;
    *(short8*)&tile[d][f0 + 8] = s1;
  }
  __syncthreads();
  {
    const int f = t >> 2, d0 = (t & 3) * 16;
    short8 o0, o1;
#pragma unroll
    for (int j = 0; j < 8; ++j) o0[j] = tile[d0 + j][f];
#pragma unroll
    for (int j = 0; j < 8; ++j) o1[j] = tile[d0 + 8 + j][f];
    short* dst = Wth + (size_t)(ft * 64 + f) * H_DIM + dt * 64 + d0;
    *(short8*)(dst) = o0;
    *(short8*)(dst + 8) = o1;
  }
}

// ---------------- Phase 1: 256^2 8-wave 3-phase GEMM ----------------
// R10: all 24 ds_reads issue at P0 (buffer stable across the K-tile); partial
// lgkmcnt(8) covers afA+bf0+bf1; afB's 8 drain at P1-end. Stages placed only
// over slabs whose readers drained before the preceding barrier.
#define BAR __builtin_amdgcn_s_barrier();
#define SGB0 __builtin_amdgcn_sched_barrier(0);
#define WAITL { asm volatile("s_waitcnt lgkmcnt(0)" ::: "memory"); __builtin_amdgcn_sched_barrier(0); }
#define WAITL8 { asm volatile("s_waitcnt lgkmcnt(8)" ::: "memory"); __builtin_amdgcn_sched_barrier(0); }
#define PRIO1 __builtin_amdgcn_s_setprio(1);
#define PRIO0 __builtin_amdgcn_s_setprio(0);

#define STG(isA, slab, ktn) \
  gload16(((isA) ? Ag : Bg) + (size_t)(slab) * 64 * H_DIM + (ktn) * 64, \
          smb + ((isA) ? 0 : 65536) + ((ktn) & 1) * 32768 + (slab) * 8192 + wub)

#define DSA(dst, mh, cbuf) { _Pragma("unroll") for (int mp = 0; mp < 4; ++mp) { \
    const int rrow = wm * 128 + (mh) * 64 + mp * 16 + lr; \
    const char* pb = smb + (cbuf) * 32768 + rrow * 128; \
    dst[mp * 2 + 0] = *(const short8*)(pb + sA0); \
    dst[mp * 2 + 1] = *(const short8*)(pb + sA1); } }

#define DSB(nh, cbuf, dst) { _Pragma("unroll") for (int np = 0; np < 2; ++np) { \
    const int brow = wn * 64 + (nh) * 32 + np * 16 + lr; \
    const char* pb = smb + 65536 + (cbuf) * 32768 + brow * 128; \
    dst[np * 2 + 0] = *(const short8*)(pb + sA0); \
    dst[np * 2 + 1] = *(const short8*)(pb + sA1); } }

#define MFMA16(afr, mh, nh, bfr) { _Pragma("unroll") for (int mp = 0; mp < 4; ++mp) \
    { _Pragma("unroll") for (int np = 0; np < 2; ++np) { \
      acc[(mh) * 4 + mp][(nh) * 2 + np] = __builtin_amdgcn_mfma_f32_16x16x32_bf16( \
          afr[mp * 2 + 0], bfr[np * 2 + 0], acc[(mh) * 4 + mp][(nh) * 2 + np], 0, 0, 0); \
      acc[(mh) * 4 + mp][(nh) * 2 + np] = __builtin_amdgcn_mfma_f32_16x16x32_bf16( \
          afr[mp * 2 + 1], bfr[np * 2 + 1], acc[(mh) * 4 + mp][(nh) * 2 + np], 0, 0, 0); } } }

__launch_bounds__(512, 2)
__global__ void qkv_8p(const short* __restrict__ n1b, const short* __restrict__ n2b,
                       const short* __restrict__ Wt,
                       const float* __restrict__ bq, const float* __restrict__ bk,
                       const float* __restrict__ bv,
                       short* __restrict__ qkv_out) {
  __shared__ short smem[65536];           // 128 KiB
  char* smb = (char*)smem;

  const int bid = blockIdx.x;
  const int v = (bid & 7) * 24 + (bid >> 3);   // XCD-chunked, bijective (192 = 8*24)
  const int gemm = v >> 4;                     // 0..11
  const int rr = v & 15;
  const int mt = rr & 3, nt = rr >> 2;
  const int bm0 = mt * 256, bn0 = nt * 256;
  const short* A = (gemm < 4) ? n1b : n2b;
  const short* B = Wt + ((size_t)gemm << 22);
  const float* bias = ((gemm < 4) ? bq : (gemm < 8) ? bk : bv) + (gemm & 3) * DH;
  short* C = qkv_out + ((size_t)gemm << 20);

  const int t = threadIdx.x;
  const int lane = t & 63, w = t >> 6;
  const int wm = w >> 2, wn = w & 3;           // 2 x 4 wave grid
  const int lr = lane & 15, lk = lane >> 4;
  const int xorv = lr & 7;
  const int sA0 = (lk ^ xorv) * 16;
  const int sA1 = ((4 + lk) ^ xorv) * 16;

  const int rowA = t >> 3;
  const int sL = (t & 7) ^ (rowA & 7);         // pre-swizzled logical slot
  const size_t wub = (size_t)w * 1024;
  const short* Ag = A + (size_t)(bm0 + rowA) * H_DIM + sL * 8;
  const short* Bg = B + (size_t)(bn0 + rowA) * H_DIM + sL * 8;

  f32x4 acc[8][4];
#pragma unroll
  for (int m = 0; m < 8; ++m)
#pragma unroll
    for (int n = 0; n < 4; ++n)
      acc[m][n] = (f32x4)(0.0f);

  short8 afA[8], afB[8], bf0[4], bf1[4];

  // prologue: stage K-tiles 0 and 1, wait tile 0 only
#pragma unroll
  for (int i = 0; i < 4; ++i) { STG(1, i, 0); }
#pragma unroll
  for (int i = 0; i < 4; ++i) { STG(0, i, 0); }
#pragma unroll
  for (int i = 0; i < 4; ++i) { STG(1, i, 1); }
#pragma unroll
  for (int i = 0; i < 4; ++i) { STG(0, i, 1); }
  asm volatile("s_waitcnt vmcnt(8)" ::: "memory");
  BAR

  const int NKT = H_DIM / 64;   // 64
  for (int kt = 0; kt < NKT; ++kt) {
    const int cb = kt & 1;
    const int dost = (kt + 2 < NKT);
    // P0: issue ALL 24 reads (afA,bf0,bf1 | afB); wait first 16; MFMA (0,0)
    DSA(afA, 0, cb)
    DSB(0, cb, bf0)
    DSB(1, cb, bf1)
    SGB0                            // pin issue order: afB strictly after the 16
    DSA(afB, 1, cb)
    WAITL8                          // afA+bf0+bf1 drained; afB's 8 in flight
    PRIO1 MFMA16(afA, 0, 0, bf0) PRIO0
    BAR                             // A02 + all B reads drained in every wave
    // P1: stage A slabs 0,2 + B slabs 0,1 (readers drained pre-BAR); MFMA (0,1)
    if (dost) { STG(1, 0, kt + 2); STG(1, 2, kt + 2); STG(0, 0, kt + 2); STG(0, 1, kt + 2); }
    PRIO1 MFMA16(afA, 0, 1, bf1) PRIO0
    WAITL                           // drain afB in every wave before the barrier
    BAR
    // P2: stage A slabs 1,3 + B slabs 2,3; 32-MFMA cluster; tail vmcnt
    if (dost) { STG(1, 1, kt + 2); STG(1, 3, kt + 2); STG(0, 2, kt + 2); STG(0, 3, kt + 2); }
    PRIO1 MFMA16(afB, 1, 1, bf1) MFMA16(afB, 1, 0, bf0) PRIO0
    if (dost)               { asm volatile("s_waitcnt vmcnt(8)" ::: "memory"); }
    else if (kt + 1 < NKT)  { asm volatile("s_waitcnt vmcnt(0)" ::: "memory"); }
    BAR                             // next tile's staging landed -> next P0 safe
  }

  // epilogue: bias + bf16 store
  float bvv[4];
#pragma unroll
  for (int n = 0; n < 4; ++n) bvv[n] = bias[bn0 + wn * 64 + n * 16 + lr];
#pragma unroll
  for (int m = 0; m < 8; ++m) {
    const int row0 = bm0 + wm * 128 + m * 16 + lk * 4;
#pragma unroll
    for (int n = 0; n < 4; ++n) {
      const int col = bn0 + wn * 64 + n * 16 + lr;
#pragma unroll
      for (int e = 0; e < 4; ++e)
        C[(size_t)(row0 + e) * DH + col] = f2bf(acc[m][n][e] + bvv[n]);
    }
  }
}

// ---------------- Phase 2: S = Q*K^T, out = S*scale.*V (f32), 128^2 2-phase ----------------
__device__ __forceinline__ void stage_tile(const short* Xrow0, size_t rowstride, int kbase,
                                           short* lds, int t) {
  const int w = t >> 6;
#pragma unroll
  for (int p = 0; p < 2; ++p) {
    const short* g = Xrow0 + (size_t)(p * 64 + (t >> 2)) * rowstride + kbase + (t & 3) * 8;
    char* l = (char*)lds + p * 4096 + w * 1024;
    gload16(g, l);
  }
}

__launch_bounds__(256)
__global__ void attn_bt(const short* __restrict__ qkv, float* __restrict__ out) {
  const int bid = blockIdx.x;
  const int v = (bid & 7) * 32 + (bid >> 3);   // XCD-chunked, bijective (256 = 8*32)
  const int h = v >> 6;
  const int tile = v & 63;
  const short* Q = qkv + (size_t)h * NROWS * DH;
  const short* K = qkv + (size_t)(4 + h) * NROWS * DH;
  const short* V = qkv + (size_t)(8 + h) * NROWS * DH;
  const int bm0 = (tile >> 3) * 128, bn0 = (tile & 7) * 128;

  __shared__ short As[2][4096];
  __shared__ short Bs[2][4096];

  const int t = threadIdx.x;
  const int lane = t & 63, w = t >> 6;
  const int wm = (w >> 1) * 64, wn = (w & 1) * 64;
  const int lr = lane & 15, lk = lane >> 4;

  const short* Arow0 = Q + (size_t)bm0 * DH;
  const short* Brow0 = K + (size_t)bn0 * DH;

  f32x4 acc[4][4];
#pragma unroll
  for (int m = 0; m < 4; ++m)
#pragma unroll
    for (int n = 0; n < 4; ++n)
      acc[m][n] = (f32x4)(0.0f);

  stage_tile(Arow0, DH, 0, &As[0][0], t);
  stage_tile(Brow0, DH, 0, &Bs[0][0], t);
  __syncthreads();

  const int NKT = DH / 32;   // 32
  int cur = 0;
  for (int kt = 0; kt < NKT; ++kt) {
    if (kt + 1 < NKT) {
      stage_tile(Arow0, DH, (kt + 1) * 32, &As[cur ^ 1][0], t);
      stage_tile(Brow0, DH, (kt + 1) * 32, &Bs[cur ^ 1][0], t);
    }
    short8 af[4], bf_[4];
#pragma unroll
    for (int m = 0; m < 4; ++m)
      af[m] = *(const short8*)((const char*)&As[cur][0] + (wm + m * 16 + lr) * 64 + lk * 16);
#pragma unroll
    for (int n = 0; n < 4; ++n)
      bf_[n] = *(const short8*)((const char*)&Bs[cur][0] + (wn + n * 16 + lr) * 64 + lk * 16);
#pragma unroll
    for (int m = 0; m < 4; ++m)
#pragma unroll
      for (int n = 0; n < 4; ++n)
        acc[m][n] = __builtin_amdgcn_mfma_f32_16x16x32_bf16(af[m], bf_[n], acc[m][n], 0, 0, 0);
    __syncthreads();
    cur ^= 1;
  }

  const float scale = 0.03125f;  // 1/sqrt(1024)
#pragma unroll
  for (int n = 0; n < 4; ++n) {
    const int col = bn0 + wn + n * 16 + lr;
#pragma unroll
    for (int m = 0; m < 4; ++m) {
      const int row0 = bm0 + wm + m * 16 + lk * 4;
#pragma unroll
      for (int r = 0; r < 4; ++r) {
        const int row = row0 + r;
        const float vv = bf2f(V[(size_t)row * DH + col]);
        out[(size_t)row * H_DIM + h * DH + col] = acc[m][n][r] * scale * vv;
      }
    }
  }
}

// ---------------- Fallback fused QKV (only if ws too small) ----------------
__launch_bounds__(256, 2)
__global__ void qkv_gemm(const float* __restrict__ node1,
                         const float* __restrict__ node2,
                         const float* __restrict__ Wq, const float* __restrict__ bq,
                         const float* __restrict__ Wk, const float* __restrict__ bk,
                         const float* __restrict__ Wv, const float* __restrict__ bv,
                         short* __restrict__ qkv_out) {
  const int gid = blockIdx.x;
  const int gemm = gid >> 6;
  const int tile = gid & 63;
  const int qkv = gemm >> 2;
  const int h = gemm & 3;
  const float* A = (qkv == 0) ? node1 : node2;
  const float* W = (qkv == 0) ? Wq : (qkv == 1 ? Wk : Wv);
  const float* bias = (qkv == 0) ? bq : (qkv == 1 ? bk : bv);
  const float* B = W + (size_t)h * H_DIM * DH;
  const float* bh = bias + h * DH;
  short* C = qkv_out + (size_t)gemm * NROWS * DH;
  const int bm0 = (tile >> 3) * 128;
  const int bn0 = (tile & 7) * 128;
  __shared__ short As[128][40];
  __shared__ short Bs[128][40];
  const int t = threadIdx.x;
  const int lane = t & 63;
  const int w = t >> 6;
  const int wm = (w >> 1) * 64;
  const int wn = (w & 1) * 64;
  const int lr = lane & 15;
  const int lk = lane >> 4;
  const int ar = t >> 3;
  const int ac = (t & 7) * 4;
  const int bfcX = t & 127;
  const int bd = (t >> 7) * 16;
  f32x4 acc[4][4];
#pragma unroll
  for (int m = 0; m < 4; ++m)
#pragma unroll
    for (int n = 0; n < 4; ++n)
      acc[m][n] = (f32x4)(0.0f);
  f32x4 rA[4];
  float rB[16];
  const float* Abase = A + (size_t)bm0 * H_DIM;
  const float* Bbase = B + bn0 + bfcX;
#pragma unroll
  for (int p = 0; p < 4; ++p)
    rA[p] = *(const f32x4*)&Abase[(size_t)(ar + 32 * p) * H_DIM + ac];
#pragma unroll
  for (int i = 0; i < 16; ++i)
    rB[i] = Bbase[(size_t)(bd + i) * DH];
  const int NKT = H_DIM / 32;
  for (int kt = 0; kt < NKT; ++kt) {
    __syncthreads();
#pragma unroll
    for (int p = 0; p < 4; ++p) {
      short4v s;
      s.x = f2bf(rA[p].x); s.y = f2bf(rA[p].y);
      s.z = f2bf(rA[p].z); s.w = f2bf(rA[p].w);
      *(short4v*)&As[ar + 32 * p][ac] = s;
    }
    {
      short8 lo, hi;
#pragma unroll
      for (int i = 0; i < 8; ++i) { lo[i] = f2bf(rB[i]); hi[i] = f2bf(rB[8 + i]); }
      *(short8*)&Bs[bfcX][bd] = lo;
      *(short8*)&Bs[bfcX][bd + 8] = hi;
    }
    __syncthreads();
    if (kt + 1 < NKT) {
      const int k0 = (kt + 1) * 32;
#pragma unroll
      for (int p = 0; p < 4; ++p)
        rA[p] = *(const f32x4*)&Abase[(size_t)(ar + 32 * p) * H_DIM + k0 + ac];
#pragma unroll
      for (int i = 0; i < 16; ++i)
        rB[i] = Bbase[(size_t)(k0 + bd + i) * DH];
    }
    short8 af[4], bf_[4];
#pragma unroll
    for (int m = 0; m < 4; ++m)
      af[m] = *(const short8*)&As[wm + m * 16 + lr][lk * 8];
#pragma unroll
    for (int n = 0; n < 4; ++n)
      bf_[n] = *(const short8*)&Bs[wn + n * 16 + lr][lk * 8];
#pragma unroll
    for (int m = 0; m < 4; ++m)
#pragma unroll
      for (int n = 0; n < 4; ++n)
        acc[m][n] = __builtin_amdgcn_mfma_f32_16x16x32_bf16(af[m], bf_[n], acc[m][n], 0, 0, 0);
  }
#pragma unroll
  for (int n = 0; n < 4; ++n) {
    const int col = bn0 + wn + n * 16 + lr;
    const float bv_ = bh[col];
#pragma unroll
    for (int m = 0; m < 4; ++m) {
      const int row0 = bm0 + wm + m * 16 + lk * 4;
#pragma unroll
      for (int r = 0; r < 4; ++r)
        C[(size_t)(row0 + r) * DH + col] = f2bf(acc[m][n][r] + bv_);
    }
  }
}

// ---------------- Phase 3: in-place LayerNorm ----------------
__launch_bounds__(256, 4)
__global__ void ln_kernel(float* __restrict__ out, const float* __restrict__ gamma,
                          const float* __restrict__ beta) {
  const int row = blockIdx.x;
  const int t = threadIdx.x;
  float* p = out + (size_t)row * H_DIM;
  f32x4 x[4];
  float s1 = 0.f, s2 = 0.f;
#pragma unroll
  for (int i = 0; i < 4; ++i) {
    x[i] = *(const f32x4*)&p[t * 4 + i * 1024];
    s1 += x[i].x + x[i].y + x[i].z + x[i].w;
    s2 += x[i].x * x[i].x + x[i].y * x[i].y + x[i].z * x[i].z + x[i].w * x[i].w;
  }
#pragma unroll
  for (int o = 32; o > 0; o >>= 1) {
    s1 += __shfl_down(s1, o);
    s2 += __shfl_down(s2, o);
  }
  __shared__ float w1[4], w2[4];
  if ((t & 63) == 0) { w1[t >> 6] = s1; w2[t >> 6] = s2; }
  __syncthreads();
  const float tot1 = w1[0] + w1[1] + w1[2] + w1[3];
  const float tot2 = w2[0] + w2[1] + w2[2] + w2[3];
  const float mu = tot1 * (1.0f / H_DIM);
  const float var = tot2 * (1.0f / H_DIM) - mu * mu;
  const float rs = rsqrtf(var + 1e-5f);
#pragma unroll
  for (int i = 0; i < 4; ++i) {
    const int c = t * 4 + i * 1024;
    const f32x4 g = *(const f32x4*)&gamma[c];
    const f32x4 b = *(const f32x4*)&beta[c];
    f32x4 y;
    y.x = (x[i].x - mu) * rs * g.x + b.x;
    y.y = (x[i].y - mu) * rs * g.y + b.y;
    y.z = (x[i].z - mu) * rs * g.z + b.z;
    y.w = (x[i].w - mu) * rs * g.w + b.w;
    *(f32x4*)&p[c] = y;
  }
}

extern "C" void kernel_launch(void* const* d_in, const int* in_sizes, int n_in,
                              void* d_out, int out_size, void* d_ws, size_t ws_size,
                              hipStream_t stream) {
  const float* node1 = (const float*)d_in[0];
  const float* node2 = (const float*)d_in[1];
  const float* Wq = (const float*)d_in[2];
  const float* bq = (const float*)d_in[3];
  const float* Wk = (const float*)d_in[4];
  const float* bk = (const float*)d_in[5];
  const float* Wv = (const float*)d_in[6];
  const float* bv = (const float*)d_in[7];
  const float* gamma = (const float*)d_in[8];
  const float* beta = (const float*)d_in[9];
  float* out = (float*)d_out;

  const size_t MB = (size_t)1 << 20;
  short* qkv = (short*)d_ws;                       // [12][1024][1024] bf16 = 24 MB
  short* n1b = qkv + ((size_t)12 << 20);           // 8 MB
  short* n2b = n1b + ((size_t)4 << 20);            // 8 MB
  short* Wt = qkv + ((size_t)20 << 20);            // 96 MB (12 transposed bf16 weights)

  if (ws_size >= 136 * MB) {
    convert_nodes<<<dim3(2048, 2), 256, 0, stream>>>(node1, node2, n1b, n2b);
    convert_w_all<<<dim3(16, 64, 12), 256, 0, stream>>>(Wq, Wk, Wv, Wt);
    qkv_8p<<<192, 512, 0, stream>>>(n1b, n2b, Wt, bq, bk, bv, qkv);
  } else {
    qkv_gemm<<<768, 256, 0, stream>>>(node1, node2, Wq, bq, Wk, bk, Wv, bv, qkv);
  }

  attn_bt<<<256, 256, 0, stream>>>(qkv, out);
  ln_kernel<<<1024, 256, 0, stream>>>(out, gamma, beta);
}

// Round 11
// 195.811 us; speedup vs baseline: 1.0231x; 1.0231x over previous
//
#include <hip/hip_runtime.h>

#define H_DIM 4096
#define DH 1024
#define NROWS 1024

typedef __attribute__((ext_vector_type(8))) short short8;
typedef __attribute__((ext_vector_type(4))) short short4v;
typedef __attribute__((ext_vector_type(4))) float f32x4;

#define AS_GLOBAL __attribute__((address_space(1)))
#define AS_LDS __attribute__((address_space(3)))

__device__ __forceinline__ short f2bf(float f) {
  union { float f; unsigned u; } v; v.f = f;
  unsigned r = v.u + 0x7fffu + ((v.u >> 16) & 1u);
  return (short)(r >> 16);
}
__device__ __forceinline__ float bf2f(short s) {
  union { unsigned u; float f; } v;
  v.u = ((unsigned)(unsigned short)s) << 16;
  return v.f;
}

__device__ __forceinline__ void gload16(const void* g, void* l) {
  __builtin_amdgcn_global_load_lds((const AS_GLOBAL void*)g, (AS_LDS void*)l, 16, 0, 0);
}

// ---------------- bf16 converts ----------------
__global__ void convert_nodes(const float* __restrict__ n1, const float* __restrict__ n2,
                              short* __restrict__ o1, short* __restrict__ o2) {
  const float* src = blockIdx.y ? n2 : n1;
  short* dst = blockIdx.y ? o2 : o1;
  const size_t i = ((size_t)blockIdx.x * 256 + threadIdx.x) * 8;
  f32x4 a = *(const f32x4*)&src[i];
  f32x4 b = *(const f32x4*)&src[i + 4];
  short8 s;
  s[0] = f2bf(a.x); s[1] = f2bf(a.y); s[2] = f2bf(a.z); s[3] = f2bf(a.w);
  s[4] = f2bf(b.x); s[5] = f2bf(b.y); s[6] = f2bf(b.z); s[7] = f2bf(b.w);
  *(short8*)&dst[i] = s;
}

// W [4][4096][1024] f32 -> Wt [12][1024][4096] bf16 (transpose per head); z picks q/k/v+head
__global__ void convert_w_all(const float* __restrict__ Wq, const float* __restrict__ Wk,
                              const float* __restrict__ Wv, short* __restrict__ Wt) {
  __shared__ short tile[64][72];
  const int z = blockIdx.z, dt = blockIdx.y, ft = blockIdx.x;
  const float* W = (z < 4) ? Wq : (z < 8) ? Wk : Wv;
  const int h = z & 3;
  const float* Wh = W + (size_t)h * H_DIM * DH;
  short* Wth = Wt + (size_t)z * DH * H_DIM;
  const int t = threadIdx.x;
  {
    const int d = t >> 2, f0 = (t & 3) * 16;
    const float* src = Wh + (size_t)(dt * 64 + d) * DH + ft * 64 + f0;
    f32x4 v0 = *(const f32x4*)(src + 0);
    f32x4 v1 = *(const f32x4*)(src + 4);
    f32x4 v2 = *(const f32x4*)(src + 8);
    f32x4 v3 = *(const f32x4*)(src + 12);
    short8 s0, s1;
    s0[0] = f2bf(v0.x); s0[1] = f2bf(v0.y); s0[2] = f2bf(v0.z); s0[3] = f2bf(v0.w);
    s0[4] = f2bf(v1.x); s0[5] = f2bf(v1.y); s0[6] = f2bf(v1.z); s0[7] = f2bf(v1.w);
    s1[0] = f2bf(v2.x); s1[1] = f2bf(v2.y); s1[2] = f2bf(v2.z); s1[3] = f2bf(v2.w);
    s1[4] = f2bf(v3.x); s1[5] = f2bf(v3.y); s1[6] = f2bf(v3.z); s1[7] = f2bf(v3.w);
    *(short8*)&tile[d][f0] = s0;
    *(short8*)&tile[d][f0 + 8] = s1;
  }
  __syncthreads();
  {
    const int f = t >> 2, d0 = (t & 3) * 16;
    short8 o0, o1;
#pragma unroll
    for (int j = 0; j < 8; ++j) o0[j] = tile[d0 + j][f];
#pragma unroll
    for (int j = 0; j < 8; ++j) o1[j] = tile[d0 + 8 + j][f];
    short* dst = Wth + (size_t)(ft * 64 + f) * H_DIM + dt * 64 + d0;
    *(short8*)(dst) = o0;
    *(short8*)(dst + 8) = o1;
  }
}

// ---------------- Phase 1: 256^2 8-wave 4-phase GEMM, 4-barrier schedule ----------------
// R9 best configuration (115 us, MfmaUtil 37.5, 0 bank conflicts): R4's proven
// dataflow (gload_lds both operands, XOR-swizzled slots, in-place freed-slab
// staging) + barrier diet (7->4/K-tile) + bf1 read-ahead to P0.
#define BAR __builtin_amdgcn_s_barrier();
#define WAITL { asm volatile("s_waitcnt lgkmcnt(0)" ::: "memory"); __builtin_amdgcn_sched_barrier(0); }
#define WAITL4 { asm volatile("s_waitcnt lgkmcnt(4)" ::: "memory"); __builtin_amdgcn_sched_barrier(0); }
#define PRIO1 __builtin_amdgcn_s_setprio(1);
#define PRIO0 __builtin_amdgcn_s_setprio(0);

#define STG(isA, slab, ktn) \
  gload16(((isA) ? Ag : Bg) + (size_t)(slab) * 64 * H_DIM + (ktn) * 64, \
          smb + ((isA) ? 0 : 65536) + ((ktn) & 1) * 32768 + (slab) * 8192 + wub)

#define DSA(mh, cbuf) { _Pragma("unroll") for (int mp = 0; mp < 4; ++mp) { \
    const int rrow = wm * 128 + (mh) * 64 + mp * 16 + lr; \
    const char* pb = smb + (cbuf) * 32768 + rrow * 128; \
    af[mp * 2 + 0] = *(const short8*)(pb + sA0); \
    af[mp * 2 + 1] = *(const short8*)(pb + sA1); } }

#define DSB(nh, cbuf, dst) { _Pragma("unroll") for (int np = 0; np < 2; ++np) { \
    const int brow = wn * 64 + (nh) * 32 + np * 16 + lr; \
    const char* pb = smb + 65536 + (cbuf) * 32768 + brow * 128; \
    dst[np * 2 + 0] = *(const short8*)(pb + sA0); \
    dst[np * 2 + 1] = *(const short8*)(pb + sA1); } }

#define MFMA16(mh, nh, bfr) { _Pragma("unroll") for (int mp = 0; mp < 4; ++mp) \
    { _Pragma("unroll") for (int np = 0; np < 2; ++np) { \
      acc[(mh) * 4 + mp][(nh) * 2 + np] = __builtin_amdgcn_mfma_f32_16x16x32_bf16( \
          af[mp * 2 + 0], bfr[np * 2 + 0], acc[(mh) * 4 + mp][(nh) * 2 + np], 0, 0, 0); \
      acc[(mh) * 4 + mp][(nh) * 2 + np] = __builtin_amdgcn_mfma_f32_16x16x32_bf16( \
          af[mp * 2 + 1], bfr[np * 2 + 1], acc[(mh) * 4 + mp][(nh) * 2 + np], 0, 0, 0); } } }

__launch_bounds__(512, 2)
__global__ void qkv_8p(const short* __restrict__ n1b, const short* __restrict__ n2b,
                       const short* __restrict__ Wt,
                       const float* __restrict__ bq, const float* __restrict__ bk,
                       const float* __restrict__ bv,
                       short* __restrict__ qkv_out) {
  __shared__ short smem[65536];           // 128 KiB
  char* smb = (char*)smem;

  const int bid = blockIdx.x;
  const int v = (bid & 7) * 24 + (bid >> 3);   // XCD-chunked, bijective (192 = 8*24)
  const int gemm = v >> 4;                     // 0..11
  const int rr = v & 15;
  const int mt = rr & 3, nt = rr >> 2;
  const int bm0 = mt * 256, bn0 = nt * 256;
  const short* A = (gemm < 4) ? n1b : n2b;
  const short* B = Wt + ((size_t)gemm << 22);
  const float* bias = ((gemm < 4) ? bq : (gemm < 8) ? bk : bv) + (gemm & 3) * DH;
  short* C = qkv_out + ((size_t)gemm << 20);

  const int t = threadIdx.x;
  const int lane = t & 63, w = t >> 6;
  const int wm = w >> 2, wn = w & 3;           // 2 x 4 wave grid
  const int lr = lane & 15, lk = lane >> 4;
  const int xorv = lr & 7;
  const int sA0 = (lk ^ xorv) * 16;
  const int sA1 = ((4 + lk) ^ xorv) * 16;

  const int rowA = t >> 3;
  const int sL = (t & 7) ^ (rowA & 7);         // pre-swizzled logical slot
  const size_t wub = (size_t)w * 1024;
  const short* Ag = A + (size_t)(bm0 + rowA) * H_DIM + sL * 8;
  const short* Bg = B + (size_t)(bn0 + rowA) * H_DIM + sL * 8;

  f32x4 acc[8][4];
#pragma unroll
  for (int m = 0; m < 8; ++m)
#pragma unroll
    for (int n = 0; n < 4; ++n)
      acc[m][n] = (f32x4)(0.0f);

  short8 af[8], bf0[4], bf1[4];

  // prologue: stage K-tiles 0 and 1, wait tile 0 only
#pragma unroll
  for (int i = 0; i < 4; ++i) { STG(1, i, 0); }
#pragma unroll
  for (int i = 0; i < 4; ++i) { STG(0, i, 0); }
#pragma unroll
  for (int i = 0; i < 4; ++i) { STG(1, i, 1); }
#pragma unroll
  for (int i = 0; i < 4; ++i) { STG(0, i, 1); }
  asm volatile("s_waitcnt vmcnt(8)" ::: "memory");
  BAR

  const int NKT = H_DIM / 64;   // 64
  for (int kt = 0; kt < NKT; ++kt) {
    const int cb = kt & 1;
    const int dost = (kt + 2 < NKT);
    // P0: issue 16 reads (afA 8, bf0 4, bf1 4); wait first 12; MFMA (0,0)
    DSA(0, cb)
    DSB(0, cb, bf0)
    DSB(1, cb, bf1)
    WAITL4                         // afA+bf0 ready; bf1's 4 stay in flight
    PRIO1 MFMA16(0, 0, bf0) PRIO0
    BAR                            // readers of A slabs 0,2 done -> P1 STGA safe
    // P1: stage A slabs 0,2 (freed at P0); MFMA (0,1)
    if (dost) { STG(1, 0, kt + 2); STG(1, 2, kt + 2); }
    WAITL                          // bf1 ready
    PRIO1 MFMA16(0, 1, bf1) PRIO0
    BAR                            // readers of B rows done -> P2 STGB safe
    // P2: read afB (slabs 1,3; af regs dead after P1 MFMA); stage B slabs 0,1
    DSA(1, cb)
    if (dost) { STG(0, 0, kt + 2); STG(0, 1, kt + 2); }
    WAITL                          // afB ready
    PRIO1 MFMA16(1, 1, bf1) PRIO0
    BAR                            // readers of A slabs 1,3 done -> P3 STGA safe
    // P3: stage B 2,3 + A 1,3; MFMA (1,0) register-only; tail vmcnt
    if (dost) { STG(0, 2, kt + 2); STG(0, 3, kt + 2); STG(1, 1, kt + 2); STG(1, 3, kt + 2); }
    PRIO1 MFMA16(1, 0, bf0) PRIO0
    if (dost)               { asm volatile("s_waitcnt vmcnt(8)" ::: "memory"); }
    else if (kt + 1 < NKT)  { asm volatile("s_waitcnt vmcnt(0)" ::: "memory"); }
    BAR                            // next tile's staging landed -> next P0 reads safe
  }

  // epilogue: bias + bf16 store
  float bvv[4];
#pragma unroll
  for (int n = 0; n < 4; ++n) bvv[n] = bias[bn0 + wn * 64 + n * 16 + lr];
#pragma unroll
  for (int m = 0; m < 8; ++m) {
    const int row0 = bm0 + wm * 128 + m * 16 + lk * 4;
#pragma unroll
    for (int n = 0; n < 4; ++n) {
      const int col = bn0 + wn * 64 + n * 16 + lr;
#pragma unroll
      for (int e = 0; e < 4; ++e)
        C[(size_t)(row0 + e) * DH + col] = f2bf(acc[m][n][e] + bvv[n]);
    }
  }
}

// ---------------- Phase 2: S = Q*K^T, out = S*scale.*V (f32), 128^2 2-phase ----------------
__device__ __forceinline__ void stage_tile(const short* Xrow0, size_t rowstride, int kbase,
                                           short* lds, int t) {
  const int w = t >> 6;
#pragma unroll
  for (int p = 0; p < 2; ++p) {
    const short* g = Xrow0 + (size_t)(p * 64 + (t >> 2)) * rowstride + kbase + (t & 3) * 8;
    char* l = (char*)lds + p * 4096 + w * 1024;
    gload16(g, l);
  }
}

__launch_bounds__(256)
__global__ void attn_bt(const short* __restrict__ qkv, float* __restrict__ out) {
  const int bid = blockIdx.x;
  const int v = (bid & 7) * 32 + (bid >> 3);   // XCD-chunked, bijective (256 = 8*32)
  const int h = v >> 6;
  const int tile = v & 63;
  const short* Q = qkv + (size_t)h * NROWS * DH;
  const short* K = qkv + (size_t)(4 + h) * NROWS * DH;
  const short* V = qkv + (size_t)(8 + h) * NROWS * DH;
  const int bm0 = (tile >> 3) * 128, bn0 = (tile & 7) * 128;

  __shared__ short As[2][4096];
  __shared__ short Bs[2][4096];

  const int t = threadIdx.x;
  const int lane = t & 63, w = t >> 6;
  const int wm = (w >> 1) * 64, wn = (w & 1) * 64;
  const int lr = lane & 15, lk = lane >> 4;

  const short* Arow0 = Q + (size_t)bm0 * DH;
  const short* Brow0 = K + (size_t)bn0 * DH;

  f32x4 acc[4][4];
#pragma unroll
  for (int m = 0; m < 4; ++m)
#pragma unroll
    for (int n = 0; n < 4; ++n)
      acc[m][n] = (f32x4)(0.0f);

  stage_tile(Arow0, DH, 0, &As[0][0], t);
  stage_tile(Brow0, DH, 0, &Bs[0][0], t);
  __syncthreads();

  const int NKT = DH / 32;   // 32
  int cur = 0;
  for (int kt = 0; kt < NKT; ++kt) {
    if (kt + 1 < NKT) {
      stage_tile(Arow0, DH, (kt + 1) * 32, &As[cur ^ 1][0], t);
      stage_tile(Brow0, DH, (kt + 1) * 32, &Bs[cur ^ 1][0], t);
    }
    short8 af[4], bf_[4];
#pragma unroll
    for (int m = 0; m < 4; ++m)
      af[m] = *(const short8*)((const char*)&As[cur][0] + (wm + m * 16 + lr) * 64 + lk * 16);
#pragma unroll
    for (int n = 0; n < 4; ++n)
      bf_[n] = *(const short8*)((const char*)&Bs[cur][0] + (wn + n * 16 + lr) * 64 + lk * 16);
#pragma unroll
    for (int m = 0; m < 4; ++m)
#pragma unroll
      for (int n = 0; n < 4; ++n)
        acc[m][n] = __builtin_amdgcn_mfma_f32_16x16x32_bf16(af[m], bf_[n], acc[m][n], 0, 0, 0);
    __syncthreads();
    cur ^= 1;
  }

  const float scale = 0.03125f;  // 1/sqrt(1024)
#pragma unroll
  for (int n = 0; n < 4; ++n) {
    const int col = bn0 + wn + n * 16 + lr;
#pragma unroll
    for (int m = 0; m < 4; ++m) {
      const int row0 = bm0 + wm + m * 16 + lk * 4;
#pragma unroll
      for (int r = 0; r < 4; ++r) {
        const int row = row0 + r;
        const float vv = bf2f(V[(size_t)row * DH + col]);
        out[(size_t)row * H_DIM + h * DH + col] = acc[m][n][r] * scale * vv;
      }
    }
  }
}

// ---------------- Fallback fused QKV (only if ws too small) ----------------
__launch_bounds__(256, 2)
__global__ void qkv_gemm(const float* __restrict__ node1,
                         const float* __restrict__ node2,
                         const float* __restrict__ Wq, const float* __restrict__ bq,
                         const float* __restrict__ Wk, const float* __restrict__ bk,
                         const float* __restrict__ Wv, const float* __restrict__ bv,
                         short* __restrict__ qkv_out) {
  const int gid = blockIdx.x;
  const int gemm = gid >> 6;
  const int tile = gid & 63;
  const int qkv = gemm >> 2;
  const int h = gemm & 3;
  const float* A = (qkv == 0) ? node1 : node2;
  const float* W = (qkv == 0) ? Wq : (qkv == 1 ? Wk : Wv);
  const float* bias = (qkv == 0) ? bq : (qkv == 1 ? bk : bv);
  const float* B = W + (size_t)h * H_DIM * DH;
  const float* bh = bias + h * DH;
  short* C = qkv_out + (size_t)gemm * NROWS * DH;
  const int bm0 = (tile >> 3) * 128;
  const int bn0 = (tile & 7) * 128;
  __shared__ short As[128][40];
  __shared__ short Bs[128][40];
  const int t = threadIdx.x;
  const int lane = t & 63;
  const int w = t >> 6;
  const int wm = (w >> 1) * 64;
  const int wn = (w & 1) * 64;
  const int lr = lane & 15;
  const int lk = lane >> 4;
  const int ar = t >> 3;
  const int ac = (t & 7) * 4;
  const int bfcX = t & 127;
  const int bd = (t >> 7) * 16;
  f32x4 acc[4][4];
#pragma unroll
  for (int m = 0; m < 4; ++m)
#pragma unroll
    for (int n = 0; n < 4; ++n)
      acc[m][n] = (f32x4)(0.0f);
  f32x4 rA[4];
  float rB[16];
  const float* Abase = A + (size_t)bm0 * H_DIM;
  const float* Bbase = B + bn0 + bfcX;
#pragma unroll
  for (int p = 0; p < 4; ++p)
    rA[p] = *(const f32x4*)&Abase[(size_t)(ar + 32 * p) * H_DIM + ac];
#pragma unroll
  for (int i = 0; i < 16; ++i)
    rB[i] = Bbase[(size_t)(bd + i) * DH];
  const int NKT = H_DIM / 32;
  for (int kt = 0; kt < NKT; ++kt) {
    __syncthreads();
#pragma unroll
    for (int p = 0; p < 4; ++p) {
      short4v s;
      s.x = f2bf(rA[p].x); s.y = f2bf(rA[p].y);
      s.z = f2bf(rA[p].z); s.w = f2bf(rA[p].w);
      *(short4v*)&As[ar + 32 * p][ac] = s;
    }
    {
      short8 lo, hi;
#pragma unroll
      for (int i = 0; i < 8; ++i) { lo[i] = f2bf(rB[i]); hi[i] = f2bf(rB[8 + i]); }
      *(short8*)&Bs[bfcX][bd] = lo;
      *(short8*)&Bs[bfcX][bd + 8] = hi;
    }
    __syncthreads();
    if (kt + 1 < NKT) {
      const int k0 = (kt + 1) * 32;
#pragma unroll
      for (int p = 0; p < 4; ++p)
        rA[p] = *(const f32x4*)&Abase[(size_t)(ar + 32 * p) * H_DIM + k0 + ac];
#pragma unroll
      for (int i = 0; i < 16; ++i)
        rB[i] = Bbase[(size_t)(k0 + bd + i) * DH];
    }
    short8 af[4], bf_[4];
#pragma unroll
    for (int m = 0; m < 4; ++m)
      af[m] = *(const short8*)&As[wm + m * 16 + lr][lk * 8];
#pragma unroll
    for (int n = 0; n < 4; ++n)
      bf_[n] = *(const short8*)&Bs[wn + n * 16 + lr][lk * 8];
#pragma unroll
    for (int m = 0; m < 4; ++m)
#pragma unroll
      for (int n = 0; n < 4; ++n)
        acc[m][n] = __builtin_amdgcn_mfma_f32_16x16x32_bf16(af[m], bf_[n], acc[m][n], 0, 0, 0);
  }
#pragma unroll
  for (int n = 0; n < 4; ++n) {
    const int col = bn0 + wn + n * 16 + lr;
    const float bv_ = bh[col];
#pragma unroll
    for (int m = 0; m < 4; ++m) {
      const int row0 = bm0 + wm + m * 16 + lk * 4;
#pragma unroll
      for (int r = 0; r < 4; ++r)
        C[(size_t)(row0 + r) * DH + col] = f2bf(acc[m][n][r] + bv_);
    }
  }
}

// ---------------- Phase 3: in-place LayerNorm ----------------
__launch_bounds__(256, 4)
__global__ void ln_kernel(float* __restrict__ out, const float* __restrict__ gamma,
                          const float* __restrict__ beta) {
  const int row = blockIdx.x;
  const int t = threadIdx.x;
  float* p = out + (size_t)row * H_DIM;
  f32x4 x[4];
  float s1 = 0.f, s2 = 0.f;
#pragma unroll
  for (int i = 0; i < 4; ++i) {
    x[i] = *(const f32x4*)&p[t * 4 + i * 1024];
    s1 += x[i].x + x[i].y + x[i].z + x[i].w;
    s2 += x[i].x * x[i].x + x[i].y * x[i].y + x[i].z * x[i].z + x[i].w * x[i].w;
  }
#pragma unroll
  for (int o = 32; o > 0; o >>= 1) {
    s1 += __shfl_down(s1, o);
    s2 += __shfl_down(s2, o);
  }
  __shared__ float w1[4], w2[4];
  if ((t & 63) == 0) { w1[t >> 6] = s1; w2[t >> 6] = s2; }
  __syncthreads();
  const float tot1 = w1[0] + w1[1] + w1[2] + w1[3];
  const float tot2 = w2[0] + w2[1] + w2[2] + w2[3];
  const float mu = tot1 * (1.0f / H_DIM);
  const float var = tot2 * (1.0f / H_DIM) - mu * mu;
  const float rs = rsqrtf(var + 1e-5f);
#pragma unroll
  for (int i = 0; i < 4; ++i) {
    const int c = t * 4 + i * 1024;
    const f32x4 g = *(const f32x4*)&gamma[c];
    const f32x4 b = *(const f32x4*)&beta[c];
    f32x4 y;
    y.x = (x[i].x - mu) * rs * g.x + b.x;
    y.y = (x[i].y - mu) * rs * g.y + b.y;
    y.z = (x[i].z - mu) * rs * g.z + b.z;
    y.w = (x[i].w - mu) * rs * g.w + b.w;
    *(f32x4*)&p[c] = y;
  }
}

extern "C" void kernel_launch(void* const* d_in, const int* in_sizes, int n_in,
                              void* d_out, int out_size, void* d_ws, size_t ws_size,
                              hipStream_t stream) {
  const float* node1 = (const float*)d_in[0];
  const float* node2 = (const float*)d_in[1];
  const float* Wq = (const float*)d_in[2];
  const float* bq = (const float*)d_in[3];
  const float* Wk = (const float*)d_in[4];
  const float* bk = (const float*)d_in[5];
  const float* Wv = (const float*)d_in[6];
  const float* bv = (const float*)d_in[7];
  const float* gamma = (const float*)d_in[8];
  const float* beta = (const float*)d_in[9];
  float* out = (float*)d_out;

  const size_t MB = (size_t)1 << 20;
  short* qkv = (short*)d_ws;                       // [12][1024][1024] bf16 = 24 MB
  short* n1b = qkv + ((size_t)12 << 20);           // 8 MB
  short* n2b = n1b + ((size_t)4 << 20);            // 8 MB
  short* Wt = qkv + ((size_t)20 << 20);            // 96 MB (12 transposed bf16 weights)

  if (ws_size >= 136 * MB) {
    convert_nodes<<<dim3(2048, 2), 256, 0, stream>>>(node1, node2, n1b, n2b);
    convert_w_all<<<dim3(16, 64, 12), 256, 0, stream>>>(Wq, Wk, Wv, Wt);
    qkv_8p<<<192, 512, 0, stream>>>(n1b, n2b, Wt, bq, bk, bv, qkv);
  } else {
    qkv_gemm<<<768, 256, 0, stream>>>(node1, node2, Wq, bq, Wk, bk, Wv, bv, qkv);
  }

  attn_bt<<<256, 256, 0, stream>>>(qkv, out);
  ln_kernel<<<1024, 256, 0, stream>>>(out, gamma, beta);
}

// Round 12
// 191.754 us; speedup vs baseline: 1.0447x; 1.0212x over previous
//
#include <hip/hip_runtime.h>

#define H_DIM 4096
#define DH 1024
#define NROWS 1024

typedef __attribute__((ext_vector_type(8))) short short8;
typedef __attribute__((ext_vector_type(4))) short short4v;
typedef __attribute__((ext_vector_type(4))) float f32x4;

#define AS_GLOBAL __attribute__((address_space(1)))
#define AS_LDS __attribute__((address_space(3)))

__device__ __forceinline__ short f2bf(float f) {
  union { float f; unsigned u; } v; v.f = f;
  unsigned r = v.u + 0x7fffu + ((v.u >> 16) & 1u);
  return (short)(r >> 16);
}
__device__ __forceinline__ float bf2f(short s) {
  union { unsigned u; float f; } v;
  v.u = ((unsigned)(unsigned short)s) << 16;
  return v.f;
}

__device__ __forceinline__ void gload16(const void* g, void* l) {
  __builtin_amdgcn_global_load_lds((const AS_GLOBAL void*)g, (AS_LDS void*)l, 16, 0, 0);
}

// ---------------- merged bf16 converts: z<12 = W transpose, z==12 = nodes ----------------
__global__ void convert_all(const float* __restrict__ Wq, const float* __restrict__ Wk,
                            const float* __restrict__ Wv,
                            const float* __restrict__ n1, const float* __restrict__ n2,
                            short* __restrict__ Wt, short* __restrict__ o1,
                            short* __restrict__ o2) {
  const int z = blockIdx.z;
  const int t = threadIdx.x;
  if (z == 12) {
    // nodes: 1024 blocks x 256 thr x 32 elems = 8M f32
    const int b = blockIdx.y * 16 + blockIdx.x;      // 0..1023
    const float* src = (b < 512) ? n1 : n2;
    short* dst = (b < 512) ? o1 : o2;
    const size_t base = (size_t)(b & 511) * 8192;
#pragma unroll
    for (int it = 0; it < 4; ++it) {
      const size_t i = base + it * 2048 + t * 8;
      f32x4 a = *(const f32x4*)&src[i];
      f32x4 c = *(const f32x4*)&src[i + 4];
      short8 s;
      s[0] = f2bf(a.x); s[1] = f2bf(a.y); s[2] = f2bf(a.z); s[3] = f2bf(a.w);
      s[4] = f2bf(c.x); s[5] = f2bf(c.y); s[6] = f2bf(c.z); s[7] = f2bf(c.w);
      *(short8*)&dst[i] = s;
    }
    return;
  }
  // W [4][4096][1024] f32 -> Wt [12][1024][4096] bf16 (transpose per head)
  __shared__ short tile[64][72];
  const int dt = blockIdx.y, ft = blockIdx.x;
  const float* W = (z < 4) ? Wq : (z < 8) ? Wk : Wv;
  const int h = z & 3;
  const float* Wh = W + (size_t)h * H_DIM * DH;
  short* Wth = Wt + (size_t)z * DH * H_DIM;
  {
    const int d = t >> 2, f0 = (t & 3) * 16;
    const float* src = Wh + (size_t)(dt * 64 + d) * DH + ft * 64 + f0;
    f32x4 v0 = *(const f32x4*)(src + 0);
    f32x4 v1 = *(const f32x4*)(src + 4);
    f32x4 v2 = *(const f32x4*)(src + 8);
    f32x4 v3 = *(const f32x4*)(src + 12);
    short8 s0, s1;
    s0[0] = f2bf(v0.x); s0[1] = f2bf(v0.y); s0[2] = f2bf(v0.z); s0[3] = f2bf(v0.w);
    s0[4] = f2bf(v1.x); s0[5] = f2bf(v1.y); s0[6] = f2bf(v1.z); s0[7] = f2bf(v1.w);
    s1[0] = f2bf(v2.x); s1[1] = f2bf(v2.y); s1[2] = f2bf(v2.z); s1[3] = f2bf(v2.w);
    s1[4] = f2bf(v3.x); s1[5] = f2bf(v3.y); s1[6] = f2bf(v3.z); s1[7] = f2bf(v3.w);
    *(short8*)&tile[d][f0] = s0;
    *(short8*)&tile[d][f0 + 8] = s1;
  }
  __syncthreads();
  {
    const int f = t >> 2, d0 = (t & 3) * 16;
    short8 o0, o1v;
#pragma unroll
    for (int j = 0; j < 8; ++j) o0[j] = tile[d0 + j][f];
#pragma unroll
    for (int j = 0; j < 8; ++j) o1v[j] = tile[d0 + 8 + j][f];
    short* dst = Wth + (size_t)(ft * 64 + f) * H_DIM + dt * 64 + d0;
    *(short8*)(dst) = o0;
    *(short8*)(dst + 8) = o1v;
  }
}

// ---------------- Phase 1: 256^2 8-wave 4-phase GEMM, 4-barrier schedule (R9 best) ----------------
#define BAR __builtin_amdgcn_s_barrier();
#define WAITL { asm volatile("s_waitcnt lgkmcnt(0)" ::: "memory"); __builtin_amdgcn_sched_barrier(0); }
#define WAITL4 { asm volatile("s_waitcnt lgkmcnt(4)" ::: "memory"); __builtin_amdgcn_sched_barrier(0); }
#define PRIO1 __builtin_amdgcn_s_setprio(1);
#define PRIO0 __builtin_amdgcn_s_setprio(0);

#define STG(isA, slab, ktn) \
  gload16(((isA) ? Ag : Bg) + (size_t)(slab) * 64 * H_DIM + (ktn) * 64, \
          smb + ((isA) ? 0 : 65536) + ((ktn) & 1) * 32768 + (slab) * 8192 + wub)

#define DSA(mh, cbuf) { _Pragma("unroll") for (int mp = 0; mp < 4; ++mp) { \
    const int rrow = wm * 128 + (mh) * 64 + mp * 16 + lr; \
    const char* pb = smb + (cbuf) * 32768 + rrow * 128; \
    af[mp * 2 + 0] = *(const short8*)(pb + sA0); \
    af[mp * 2 + 1] = *(const short8*)(pb + sA1); } }

#define DSB(nh, cbuf, dst) { _Pragma("unroll") for (int np = 0; np < 2; ++np) { \
    const int brow = wn * 64 + (nh) * 32 + np * 16 + lr; \
    const char* pb = smb + 65536 + (cbuf) * 32768 + brow * 128; \
    dst[np * 2 + 0] = *(const short8*)(pb + sA0); \
    dst[np * 2 + 1] = *(const short8*)(pb + sA1); } }

#define MFMA16(mh, nh, bfr) { _Pragma("unroll") for (int mp = 0; mp < 4; ++mp) \
    { _Pragma("unroll") for (int np = 0; np < 2; ++np) { \
      acc[(mh) * 4 + mp][(nh) * 2 + np] = __builtin_amdgcn_mfma_f32_16x16x32_bf16( \
          af[mp * 2 + 0], bfr[np * 2 + 0], acc[(mh) * 4 + mp][(nh) * 2 + np], 0, 0, 0); \
      acc[(mh) * 4 + mp][(nh) * 2 + np] = __builtin_amdgcn_mfma_f32_16x16x32_bf16( \
          af[mp * 2 + 1], bfr[np * 2 + 1], acc[(mh) * 4 + mp][(nh) * 2 + np], 0, 0, 0); } } }

__launch_bounds__(512, 2)
__global__ void qkv_8p(const short* __restrict__ n1b, const short* __restrict__ n2b,
                       const short* __restrict__ Wt,
                       const float* __restrict__ bq, const float* __restrict__ bk,
                       const float* __restrict__ bv,
                       short* __restrict__ qkv_out) {
  __shared__ short smem[65536];           // 128 KiB
  char* smb = (char*)smem;

  const int bid = blockIdx.x;
  const int v = (bid & 7) * 24 + (bid >> 3);   // XCD-chunked, bijective (192 = 8*24)
  const int gemm = v >> 4;                     // 0..11
  const int rr = v & 15;
  const int mt = rr & 3, nt = rr >> 2;
  const int bm0 = mt * 256, bn0 = nt * 256;
  const short* A = (gemm < 4) ? n1b : n2b;
  const short* B = Wt + ((size_t)gemm << 22);
  const float* bias = ((gemm < 4) ? bq : (gemm < 8) ? bk : bv) + (gemm & 3) * DH;
  short* C = qkv_out + ((size_t)gemm << 20);

  const int t = threadIdx.x;
  const int lane = t & 63, w = t >> 6;
  const int wm = w >> 2, wn = w & 3;           // 2 x 4 wave grid
  const int lr = lane & 15, lk = lane >> 4;
  const int xorv = lr & 7;
  const int sA0 = (lk ^ xorv) * 16;
  const int sA1 = ((4 + lk) ^ xorv) * 16;

  const int rowA = t >> 3;
  const int sL = (t & 7) ^ (rowA & 7);         // pre-swizzled logical slot
  const size_t wub = (size_t)w * 1024;
  const short* Ag = A + (size_t)(bm0 + rowA) * H_DIM + sL * 8;
  const short* Bg = B + (size_t)(bn0 + rowA) * H_DIM + sL * 8;

  f32x4 acc[8][4];
#pragma unroll
  for (int m = 0; m < 8; ++m)
#pragma unroll
    for (int n = 0; n < 4; ++n)
      acc[m][n] = (f32x4)(0.0f);

  short8 af[8], bf0[4], bf1[4];

  // prologue: stage K-tiles 0 and 1, wait tile 0 only
#pragma unroll
  for (int i = 0; i < 4; ++i) { STG(1, i, 0); }
#pragma unroll
  for (int i = 0; i < 4; ++i) { STG(0, i, 0); }
#pragma unroll
  for (int i = 0; i < 4; ++i) { STG(1, i, 1); }
#pragma unroll
  for (int i = 0; i < 4; ++i) { STG(0, i, 1); }
  asm volatile("s_waitcnt vmcnt(8)" ::: "memory");
  BAR

  const int NKT = H_DIM / 64;   // 64
  for (int kt = 0; kt < NKT; ++kt) {
    const int cb = kt & 1;
    const int dost = (kt + 2 < NKT);
    // P0: issue 16 reads (afA 8, bf0 4, bf1 4); wait first 12; MFMA (0,0)
    DSA(0, cb)
    DSB(0, cb, bf0)
    DSB(1, cb, bf1)
    WAITL4                         // afA+bf0 ready; bf1's 4 stay in flight
    PRIO1 MFMA16(0, 0, bf0) PRIO0
    BAR                            // readers of A slabs 0,2 done -> P1 STGA safe
    // P1: stage A slabs 0,2 (freed at P0); MFMA (0,1)
    if (dost) { STG(1, 0, kt + 2); STG(1, 2, kt + 2); }
    WAITL                          // bf1 ready
    PRIO1 MFMA16(0, 1, bf1) PRIO0
    BAR                            // readers of B rows done -> P2 STGB safe
    // P2: read afB (slabs 1,3; af regs dead after P1 MFMA); stage B slabs 0,1
    DSA(1, cb)
    if (dost) { STG(0, 0, kt + 2); STG(0, 1, kt + 2); }
    WAITL                          // afB ready
    PRIO1 MFMA16(1, 1, bf1) PRIO0
    BAR                            // readers of A slabs 1,3 done -> P3 STGA safe
    // P3: stage B 2,3 + A 1,3; MFMA (1,0) register-only; tail vmcnt
    if (dost) { STG(0, 2, kt + 2); STG(0, 3, kt + 2); STG(1, 1, kt + 2); STG(1, 3, kt + 2); }
    PRIO1 MFMA16(1, 0, bf0) PRIO0
    if (dost)               { asm volatile("s_waitcnt vmcnt(8)" ::: "memory"); }
    else if (kt + 1 < NKT)  { asm volatile("s_waitcnt vmcnt(0)" ::: "memory"); }
    BAR                            // next tile's staging landed -> next P0 reads safe
  }

  // epilogue: bias + bf16 store
  float bvv[4];
#pragma unroll
  for (int n = 0; n < 4; ++n) bvv[n] = bias[bn0 + wn * 64 + n * 16 + lr];
#pragma unroll
  for (int m = 0; m < 8; ++m) {
    const int row0 = bm0 + wm * 128 + m * 16 + lk * 4;
#pragma unroll
    for (int n = 0; n < 4; ++n) {
      const int col = bn0 + wn * 64 + n * 16 + lr;
#pragma unroll
      for (int e = 0; e < 4; ++e)
        C[(size_t)(row0 + e) * DH + col] = f2bf(acc[m][n][e] + bvv[n]);
    }
  }
}

// ---------------- Phase 2: S = Q*K^T, preln = bf16(S*scale.*V), 128^2 2-phase ----------------
__device__ __forceinline__ void stage_tile(const short* Xrow0, size_t rowstride, int kbase,
                                           short* lds, int t) {
  const int w = t >> 6;
#pragma unroll
  for (int p = 0; p < 2; ++p) {
    const short* g = Xrow0 + (size_t)(p * 64 + (t >> 2)) * rowstride + kbase + (t & 3) * 8;
    char* l = (char*)lds + p * 4096 + w * 1024;
    gload16(g, l);
  }
}

__launch_bounds__(256)
__global__ void attn_bt(const short* __restrict__ qkv, short* __restrict__ preln) {
  const int bid = blockIdx.x;
  const int v = (bid & 7) * 32 + (bid >> 3);   // XCD-chunked, bijective (256 = 8*32)
  const int h = v >> 6;
  const int tile = v & 63;
  const short* Q = qkv + (size_t)h * NROWS * DH;
  const short* K = qkv + (size_t)(4 + h) * NROWS * DH;
  const short* V = qkv + (size_t)(8 + h) * NROWS * DH;
  const int bm0 = (tile >> 3) * 128, bn0 = (tile & 7) * 128;

  __shared__ short As[2][4096];
  __shared__ short Bs[2][4096];

  const int t = threadIdx.x;
  const int lane = t & 63, w = t >> 6;
  const int wm = (w >> 1) * 64, wn = (w & 1) * 64;
  const int lr = lane & 15, lk = lane >> 4;

  const short* Arow0 = Q + (size_t)bm0 * DH;
  const short* Brow0 = K + (size_t)bn0 * DH;

  f32x4 acc[4][4];
#pragma unroll
  for (int m = 0; m < 4; ++m)
#pragma unroll
    for (int n = 0; n < 4; ++n)
      acc[m][n] = (f32x4)(0.0f);

  stage_tile(Arow0, DH, 0, &As[0][0], t);
  stage_tile(Brow0, DH, 0, &Bs[0][0], t);
  __syncthreads();

  const int NKT = DH / 32;   // 32
  int cur = 0;
  for (int kt = 0; kt < NKT; ++kt) {
    if (kt + 1 < NKT) {
      stage_tile(Arow0, DH, (kt + 1) * 32, &As[cur ^ 1][0], t);
      stage_tile(Brow0, DH, (kt + 1) * 32, &Bs[cur ^ 1][0], t);
    }
    short8 af[4], bf_[4];
#pragma unroll
    for (int m = 0; m < 4; ++m)
      af[m] = *(const short8*)((const char*)&As[cur][0] + (wm + m * 16 + lr) * 64 + lk * 16);
#pragma unroll
    for (int n = 0; n < 4; ++n)
      bf_[n] = *(const short8*)((const char*)&Bs[cur][0] + (wn + n * 16 + lr) * 64 + lk * 16);
#pragma unroll
    for (int m = 0; m < 4; ++m)
#pragma unroll
      for (int n = 0; n < 4; ++n)
        acc[m][n] = __builtin_amdgcn_mfma_f32_16x16x32_bf16(af[m], bf_[n], acc[m][n], 0, 0, 0);
    __syncthreads();
    cur ^= 1;
  }

  const float scale = 0.03125f;  // 1/sqrt(1024)
#pragma unroll
  for (int n = 0; n < 4; ++n) {
    const int col = bn0 + wn + n * 16 + lr;
#pragma unroll
    for (int m = 0; m < 4; ++m) {
      const int row0 = bm0 + wm + m * 16 + lk * 4;
#pragma unroll
      for (int r = 0; r < 4; ++r) {
        const int row = row0 + r;
        const float vv = bf2f(V[(size_t)row * DH + col]);
        preln[(size_t)row * H_DIM + h * DH + col] = f2bf(acc[m][n][r] * scale * vv);
      }
    }
  }
}

// ---------------- Fallback fused QKV (only if ws too small) ----------------
__launch_bounds__(256, 2)
__global__ void qkv_gemm(const float* __restrict__ node1,
                         const float* __restrict__ node2,
                         const float* __restrict__ Wq, const float* __restrict__ bq,
                         const float* __restrict__ Wk, const float* __restrict__ bk,
                         const float* __restrict__ Wv, const float* __restrict__ bv,
                         short* __restrict__ qkv_out) {
  const int gid = blockIdx.x;
  const int gemm = gid >> 6;
  const int tile = gid & 63;
  const int qkv = gemm >> 2;
  const int h = gemm & 3;
  const float* A = (qkv == 0) ? node1 : node2;
  const float* W = (qkv == 0) ? Wq : (qkv == 1 ? Wk : Wv);
  const float* bias = (qkv == 0) ? bq : (qkv == 1 ? bk : bv);
  const float* B = W + (size_t)h * H_DIM * DH;
  const float* bh = bias + h * DH;
  short* C = qkv_out + (size_t)gemm * NROWS * DH;
  const int bm0 = (tile >> 3) * 128;
  const int bn0 = (tile & 7) * 128;
  __shared__ short As[128][40];
  __shared__ short Bs[128][40];
  const int t = threadIdx.x;
  const int lane = t & 63;
  const int w = t >> 6;
  const int wm = (w >> 1) * 64;
  const int wn = (w & 1) * 64;
  const int lr = lane & 15;
  const int lk = lane >> 4;
  const int ar = t >> 3;
  const int ac = (t & 7) * 4;
  const int bfcX = t & 127;
  const int bd = (t >> 7) * 16;
  f32x4 acc[4][4];
#pragma unroll
  for (int m = 0; m < 4; ++m)
#pragma unroll
    for (int n = 0; n < 4; ++n)
      acc[m][n] = (f32x4)(0.0f);
  f32x4 rA[4];
  float rB[16];
  const float* Abase = A + (size_t)bm0 * H_DIM;
  const float* Bbase = B + bn0 + bfcX;
#pragma unroll
  for (int p = 0; p < 4; ++p)
    rA[p] = *(const f32x4*)&Abase[(size_t)(ar + 32 * p) * H_DIM + ac];
#pragma unroll
  for (int i = 0; i < 16; ++i)
    rB[i] = Bbase[(size_t)(bd + i) * DH];
  const int NKT = H_DIM / 32;
  for (int kt = 0; kt < NKT; ++kt) {
    __syncthreads();
#pragma unroll
    for (int p = 0; p < 4; ++p) {
      short4v s;
      s.x = f2bf(rA[p].x); s.y = f2bf(rA[p].y);
      s.z = f2bf(rA[p].z); s.w = f2bf(rA[p].w);
      *(short4v*)&As[ar + 32 * p][ac] = s;
    }
    {
      short8 lo, hi;
#pragma unroll
      for (int i = 0; i < 8; ++i) { lo[i] = f2bf(rB[i]); hi[i] = f2bf(rB[8 + i]); }
      *(short8*)&Bs[bfcX][bd] = lo;
      *(short8*)&Bs[bfcX][bd + 8] = hi;
    }
    __syncthreads();
    if (kt + 1 < NKT) {
      const int k0 = (kt + 1) * 32;
#pragma unroll
      for (int p = 0; p < 4; ++p)
        rA[p] = *(const f32x4*)&Abase[(size_t)(ar + 32 * p) * H_DIM + k0 + ac];
#pragma unroll
      for (int i = 0; i < 16; ++i)
        rB[i] = Bbase[(size_t)(k0 + bd + i) * DH];
    }
    short8 af[4], bf_[4];
#pragma unroll
    for (int m = 0; m < 4; ++m)
      af[m] = *(const short8*)&As[wm + m * 16 + lr][lk * 8];
#pragma unroll
    for (int n = 0; n < 4; ++n)
      bf_[n] = *(const short8*)&Bs[wn + n * 16 + lr][lk * 8];
#pragma unroll
    for (int m = 0; m < 4; ++m)
#pragma unroll
      for (int n = 0; n < 4; ++n)
        acc[m][n] = __builtin_amdgcn_mfma_f32_16x16x32_bf16(af[m], bf_[n], acc[m][n], 0, 0, 0);
  }
#pragma unroll
  for (int n = 0; n < 4; ++n) {
    const int col = bn0 + wn + n * 16 + lr;
    const float bv_ = bh[col];
#pragma unroll
    for (int m = 0; m < 4; ++m) {
      const int row0 = bm0 + wm + m * 16 + lk * 4;
#pragma unroll
      for (int r = 0; r < 4; ++r)
        C[(size_t)(row0 + r) * DH + col] = f2bf(acc[m][n][r] + bv_);
    }
  }
}

// ---------------- Phase 3: LayerNorm, bf16 in -> f32 out ----------------
__launch_bounds__(256, 4)
__global__ void ln_kernel(const short* __restrict__ preln, float* __restrict__ out,
                          const float* __restrict__ gamma, const float* __restrict__ beta) {
  const int row = blockIdx.x;
  const int t = threadIdx.x;
  const short* p = preln + (size_t)row * H_DIM;
  float x[16];
  float s1 = 0.f, s2 = 0.f;
#pragma unroll
  for (int i = 0; i < 2; ++i) {
    short8 v = *(const short8*)&p[t * 8 + i * 2048];
#pragma unroll
    for (int j = 0; j < 8; ++j) {
      const float f = bf2f(v[j]);
      x[i * 8 + j] = f;
      s1 += f; s2 += f * f;
    }
  }
#pragma unroll
  for (int o = 32; o > 0; o >>= 1) {
    s1 += __shfl_down(s1, o);
    s2 += __shfl_down(s2, o);
  }
  __shared__ float w1[4], w2[4];
  if ((t & 63) == 0) { w1[t >> 6] = s1; w2[t >> 6] = s2; }
  __syncthreads();
  const float tot1 = w1[0] + w1[1] + w1[2] + w1[3];
  const float tot2 = w2[0] + w2[1] + w2[2] + w2[3];
  const float mu = tot1 * (1.0f / H_DIM);
  const float var = tot2 * (1.0f / H_DIM) - mu * mu;
  const float rs = rsqrtf(var + 1e-5f);
  float* po = out + (size_t)row * H_DIM;
#pragma unroll
  for (int i = 0; i < 2; ++i) {
    const int c = t * 8 + i * 2048;
    const f32x4 g0 = *(const f32x4*)&gamma[c];
    const f32x4 g1 = *(const f32x4*)&gamma[c + 4];
    const f32x4 b0 = *(const f32x4*)&beta[c];
    const f32x4 b1 = *(const f32x4*)&beta[c + 4];
    f32x4 y0, y1;
    y0.x = (x[i * 8 + 0] - mu) * rs * g0.x + b0.x;
    y0.y = (x[i * 8 + 1] - mu) * rs * g0.y + b0.y;
    y0.z = (x[i * 8 + 2] - mu) * rs * g0.z + b0.z;
    y0.w = (x[i * 8 + 3] - mu) * rs * g0.w + b0.w;
    y1.x = (x[i * 8 + 4] - mu) * rs * g1.x + b1.x;
    y1.y = (x[i * 8 + 5] - mu) * rs * g1.y + b1.y;
    y1.z = (x[i * 8 + 6] - mu) * rs * g1.z + b1.z;
    y1.w = (x[i * 8 + 7] - mu) * rs * g1.w + b1.w;
    *(f32x4*)&po[c] = y0;
    *(f32x4*)&po[c + 4] = y1;
  }
}

extern "C" void kernel_launch(void* const* d_in, const int* in_sizes, int n_in,
                              void* d_out, int out_size, void* d_ws, size_t ws_size,
                              hipStream_t stream) {
  const float* node1 = (const float*)d_in[0];
  const float* node2 = (const float*)d_in[1];
  const float* Wq = (const float*)d_in[2];
  const float* bq = (const float*)d_in[3];
  const float* Wk = (const float*)d_in[4];
  const float* bk = (const float*)d_in[5];
  const float* Wv = (const float*)d_in[6];
  const float* bv = (const float*)d_in[7];
  const float* gamma = (const float*)d_in[8];
  const float* beta = (const float*)d_in[9];
  float* out = (float*)d_out;

  const size_t MB = (size_t)1 << 20;
  short* qkv = (short*)d_ws;                       // [12][1024][1024] bf16 = 24 MB
  short* n1b = qkv + ((size_t)12 << 20);           // 8 MB (reused as preln after qkv_8p)
  short* n2b = n1b + ((size_t)4 << 20);            // 8 MB
  short* Wt = qkv + ((size_t)20 << 20);            // 96 MB (12 transposed bf16 weights)
  short* preln = n1b;                              // alias: n1b dead after qkv_8p

  if (ws_size >= 136 * MB) {
    convert_all<<<dim3(16, 64, 13), 256, 0, stream>>>(Wq, Wk, Wv, node1, node2,
                                                      Wt, n1b, n2b);
    qkv_8p<<<192, 512, 0, stream>>>(n1b, n2b, Wt, bq, bk, bv, qkv);
  } else {
    qkv_gemm<<<768, 256, 0, stream>>>(node1, node2, Wq, bq, Wk, bk, Wv, bv, qkv);
  }

  attn_bt<<<256, 256, 0, stream>>>(qkv, preln);
  ln_kernel<<<1024, 256, 0, stream>>>(preln, out, gamma, beta);
}